// Round 9
// baseline (224.442 us; speedup 1.0000x reference)
//
#include <hip/hip_runtime.h>

// Problem constants (fixed by setup_inputs: bs=8, N=M=4096, C=128)
#define BS 8
#define NN 4096
#define MM 4096
#define CC 128
#define XT 128            // x rows per block
#define MT 128            // y rows per m-tile
#define NMT (MM / MT)     // 32 m-tiles per block (full M sweep)
#define NXT (NN / XT)     // 32 x-tiles

#define FINF_BITS 0x7F800000u

typedef __attribute__((ext_vector_type(8))) short bf16x8;
typedef __attribute__((ext_vector_type(4))) float f32x4;

// RNE fp32 -> bf16 (inputs are finite normals)
__device__ inline ushort f2bf(float f) {
    unsigned u = __float_as_uint(f);
    unsigned r = (u + 0x7FFFu + ((u >> 16) & 1u)) >> 16;
    return (ushort)r;
}

// ---------------------------------------------------------------------------
// prep: fp32->bf16 copies + exact fp32 row norms + colmin=+inf + out=0
// (rowmin is plain-stored by ch_tile now — no init needed)
// ---------------------------------------------------------------------------
__global__ void ch_prep(const float* __restrict__ x, const float* __restrict__ y,
                        ushort* __restrict__ x16, ushort* __restrict__ y16,
                        float* __restrict__ xn, float* __restrict__ yn,
                        unsigned* __restrict__ colmin, float* __restrict__ out) {
    int gid = blockIdx.x * blockDim.x + threadIdx.x;
    size_t i = (size_t)gid * 4;

    float4 v = *(const float4*)(x + i);
    ushort4 o;
    o.x = f2bf(v.x); o.y = f2bf(v.y); o.z = f2bf(v.z); o.w = f2bf(v.w);
    *(ushort4*)(x16 + i) = o;
    float sx = v.x * v.x + v.y * v.y + v.z * v.z + v.w * v.w;

    float4 w = *(const float4*)(y + i);
    ushort4 p;
    p.x = f2bf(w.x); p.y = f2bf(w.y); p.z = f2bf(w.z); p.w = f2bf(w.w);
    *(ushort4*)(y16 + i) = p;
    float sy = w.x * w.x + w.y * w.y + w.z * w.z + w.w * w.w;

#pragma unroll
    for (int mask = 1; mask <= 16; mask <<= 1) {
        sx += __shfl_xor(sx, mask, 64);
        sy += __shfl_xor(sy, mask, 64);
    }
    if ((threadIdx.x & 31) == 0) {
        int row = gid >> 5;
        xn[row] = sx;
        yn[row] = sy;
    }
    if (gid < BS * MM) colmin[gid] = FINF_BITS;
    if (gid == 0) out[0] = 0.0f;
}

// ---------------------------------------------------------------------------
// main kernel (R9): one block per CU (grid 256 = BS x NXT, blockIdx.x=b so
// linear_id%8=b pins each batch to one XCD -> x+y L2-resident).
// 8 waves = 8 column-groups: each wave owns ALL 128 x-rows x 16 y-cols
//   -> zero y redundancy, acc = 8x f32x4 = 32 AGPR.
// x-tile in XOR-swizzled LDS (staged once). y fragments REGISTER
// DOUBLE-BUFFERED: tile mt+1's 4 yf loads issue before tile mt's MFMAs
// (load->use distance ~32 MFMAs >> L2 latency). No barriers in m-loop.
// Row d^2 mins persist in regs across full M; lc-shuffle-reduced once,
// rowtile LDS atomic, plain global store (rows block-exclusive).
// Col mins: quad-shuffle per tile + one global atomicMin per col.
// ---------------------------------------------------------------------------
__global__ __launch_bounds__(512) void ch_tile(
    const ushort* __restrict__ X, const ushort* __restrict__ Y,
    const float* __restrict__ xn, const float* __restrict__ yn,
    float* __restrict__ rowmin, unsigned* __restrict__ colmin) {

    __shared__ ushort xs[XT * CC];     // 32 KB, chunk-swizzled
    __shared__ unsigned rowtile[XT];   // 0.5 KB

    const int b  = blockIdx.x;         // 0..7  (XCD pin)
    const int xt = blockIdx.y;         // 0..31
    const int n0 = xt * XT;
    const int tid  = threadIdx.x;
    const int wave = tid >> 6;         // 0..7 = column group
    const int lane = tid & 63;
    const int lc   = lane & 15;        // A/B row, C col
    const int quad = lane >> 4;        // k-chunk, C row group
    const int ycol = wave * 16 + lc;   // y index within each m-tile

    // ---- stage x tile into swizzled LDS (16B chunk c at slot c^(row&7)) ----
    const ushort* Xb = X + ((size_t)b * NN + n0) * CC;
#pragma unroll
    for (int s = 0; s < 4; ++s) {
        int flat = s * 512 + tid;      // 2048 chunks = 128 rows x 16
        int r = flat >> 4, c = flat & 15;
        int cs = c ^ (r & 7);
        *(bf16x8*)(xs + r * CC + cs * 8) = *(const bf16x8*)(Xb + (size_t)r * CC + c * 8);
    }
    if (tid < XT) rowtile[tid] = FINF_BITS;
    __syncthreads();

    // ---- persistent per-lane state ----
    float xnr[8][4];
#pragma unroll
    for (int i = 0; i < 8; ++i) {
        float4 t = *(const float4*)(xn + (size_t)b * NN + n0 + i * 16 + quad * 4);
        xnr[i][0] = t.x; xnr[i][1] = t.y; xnr[i][2] = t.z; xnr[i][3] = t.w;
    }
    float rm[8][4];
#pragma unroll
    for (int i = 0; i < 8; ++i)
#pragma unroll
        for (int r = 0; r < 4; ++r) rm[i][r] = __builtin_inff();

    const ushort* Yb  = Y + (size_t)b * MM * CC;
    const float*  ynb = yn + (size_t)b * MM;
    const int xsw = lc & 7;

    auto loady = [&](int mt, bf16x8* yf, float& ynr) {
        const ushort* yp = Yb + (size_t)(mt * MT + ycol) * CC + quad * 8;
#pragma unroll
        for (int kt = 0; kt < 4; ++kt)
            yf[kt] = *(const bf16x8*)(yp + kt * 32);
        ynr = ynb[mt * MT + ycol];
    };

    auto compute = [&](int mt, const bf16x8* yf, float ynr) {
        f32x4 acc[8];
        const f32x4 z = {0.f, 0.f, 0.f, 0.f};
#pragma unroll
        for (int kt = 0; kt < 4; ++kt) {
            const int cs = ((kt * 4 + quad) ^ xsw) * 8;
#pragma unroll
            for (int i = 0; i < 8; ++i) {
                bf16x8 af = *(const bf16x8*)(xs + (i * 16 + lc) * CC + cs);
                acc[i] = __builtin_amdgcn_mfma_f32_16x16x32_bf16(
                    af, yf[kt], (kt == 0) ? z : acc[i], 0, 0, 0);
            }
        }
        float cmv = __builtin_inff();
#pragma unroll
        for (int i = 0; i < 8; ++i) {
            f32x4 a = acc[i];
#pragma unroll
            for (int r = 0; r < 4; ++r) {
                float d2 = xnr[i][r] + fmaf(-2.0f, a[r], ynr);
                rm[i][r] = fminf(rm[i][r], d2);
                cmv      = fminf(cmv, d2);
            }
        }
        cmv = fminf(cmv, __shfl_xor(cmv, 16, 64));
        cmv = fminf(cmv, __shfl_xor(cmv, 32, 64));
        if (quad == 0)
            atomicMin(&colmin[(size_t)b * MM + mt * MT + ycol],
                      __float_as_uint(fmaxf(cmv, 0.0f)));
    };

    // ---- software-pipelined m-loop: prefetch mt+1 while computing mt ----
    bf16x8 yfA[4], yfB[4];
    float ynrA, ynrB;
    loady(0, yfA, ynrA);
#pragma unroll 1
    for (int mt = 0; mt < NMT; mt += 2) {
        loady(mt + 1, yfB, ynrB);
        compute(mt, yfA, ynrA);
        loady((mt + 2 < NMT) ? mt + 2 : 0, yfA, ynrA);   // last reload harmless
        compute(mt + 1, yfB, ynrB);
    }

    // ---- row mins: lc-shuffle reduce, LDS atomic, plain global store ----
#pragma unroll
    for (int mask = 1; mask <= 8; mask <<= 1)
#pragma unroll
        for (int i = 0; i < 8; ++i)
#pragma unroll
            for (int r = 0; r < 4; ++r)
                rm[i][r] = fminf(rm[i][r], __shfl_xor(rm[i][r], mask, 64));
    if (lc == 0) {
#pragma unroll
        for (int i = 0; i < 8; ++i)
#pragma unroll
            for (int r = 0; r < 4; ++r)
                atomicMin(&rowtile[i * 16 + quad * 4 + r],
                          __float_as_uint(fmaxf(rm[i][r], 0.0f)));
    }
    __syncthreads();
    if (tid < XT)
        rowmin[(size_t)b * NN + n0 + tid] = __uint_as_float(rowtile[tid]);
}

// ---------------------------------------------------------------------------
// finalize: total = (sum w1*sqrt(rowmin) + sum w2*sqrt(colmin)) / 2
// ---------------------------------------------------------------------------
__global__ void ch_finalize(const float* __restrict__ rowmin,
                            const unsigned* __restrict__ colmin,
                            const float* __restrict__ w1,
                            const float* __restrict__ w2,
                            float* __restrict__ out) {
    int i = blockIdx.x * blockDim.x + threadIdx.x;
    int stride = gridDim.x * blockDim.x;
    float s = 0.f;
    for (int idx = i; idx < BS * NN; idx += stride)
        s += w1[idx] * sqrtf(rowmin[idx]) +
             w2[idx] * sqrtf(__uint_as_float(colmin[idx]));
#pragma unroll
    for (int off = 32; off > 0; off >>= 1) s += __shfl_down(s, off, 64);
    __shared__ float ls[4];
    int lane = threadIdx.x & 63, wv = threadIdx.x >> 6;
    if (lane == 0) ls[wv] = s;
    __syncthreads();
    if (threadIdx.x == 0) {
        float t = ls[0] + ls[1] + ls[2] + ls[3];
        atomicAdd(out, 0.5f * t);
    }
}

extern "C" void kernel_launch(void* const* d_in, const int* in_sizes, int n_in,
                              void* d_out, int out_size, void* d_ws, size_t ws_size,
                              hipStream_t stream) {
    const float* set1 = (const float*)d_in[0];
    const float* set2 = (const float*)d_in[1];
    const float* w1   = (const float*)d_in[2];
    const float* w2   = (const float*)d_in[3];
    float* out = (float*)d_out;

    // workspace layout (~16.5 MiB)
    ushort*   x16    = (ushort*)d_ws;                        // 8 MB
    ushort*   y16    = x16 + (size_t)BS * NN * CC;           // 8 MB
    float*    xn     = (float*)(y16 + (size_t)BS * MM * CC); // 128 KB
    float*    yn     = xn + BS * NN;                         // 128 KB
    float*    rowmin = yn + BS * MM;                         // 128 KB (d^2, plain)
    unsigned* colmin = (unsigned*)(rowmin + BS * NN);        // 128 KB (d^2 bits)

    ch_prep<<<BS * NN * CC / 4 / 256, 256, 0, stream>>>(
        set1, set2, x16, y16, xn, yn, colmin, out);

    dim3 grid(BS, NXT);   // blockIdx.x = b -> XCD pin (linear id % 8 == b)
    ch_tile<<<grid, 512, 0, stream>>>(x16, y16, xn, yn, rowmin, colmin);

    ch_finalize<<<64, 256, 0, stream>>>(rowmin, colmin, w1, w2, out);
}